// Round 1
// baseline (86.042 us; speedup 1.0000x reference)
//
#include <hip/hip_runtime.h>

// Cost volume: corr[b, dyi*9+dxi, y, x] = sum_c f1[b,c,y,x] * f2[b,c,y+dyi-4,x+dxi-4]
// (OOB f2 = 0). B=4, C=256, H=W=96, patch 9x9.
//
// Design (round 1):
//  - Each thread owns 4 consecutive x (one float4 column chunk), one y, one dy.
//    36 f32 accumulators (9 dx * 4 x) live in registers.
//  - dy split across blockIdx.x (9) to get enough waves (1296 waves, ~5/CU).
//  - f1: direct coalesced float4 load per channel (each element used by exactly
//    one thread per dy -> no sharing needed; dy-adjacent blocks re-hit L1/L2).
//  - f2: window [x0-4, x0+7] = 3 aligned float4 loads; edge chunks are
//    entirely in- or out-of-bounds (stride-4 grid), so guards are whole-vector.
//  - No LDS, no barriers; single-wave blocks.

#define NB 4
#define NC 256
#define NH 96
#define NW 96
#define MAXD 4
#define NP 9
#define XCH (NW / 4)            // 24 x-chunks per row
#define NCHUNK (NB * NH * XCH)  // 9216 chunk-threads per dy
#define PLANE (NH * NW)         // 9216 floats per (b,c) plane

__global__ __launch_bounds__(64) void costvol_kernel(
    const float* __restrict__ f1, const float* __restrict__ f2,
    float* __restrict__ out)
{
    const int dyi = blockIdx.x;                       // 0..8
    const int ch  = blockIdx.y * 64 + threadIdx.x;    // 0..9215
    const int b   = ch / (NH * XCH);
    const int rem = ch - b * (NH * XCH);
    const int y   = rem / XCH;
    const int x0  = (rem - y * XCH) * 4;
    const int y2  = y + dyi - MAXD;

    float acc[NP][4];
#pragma unroll
    for (int i = 0; i < NP; ++i)
#pragma unroll
        for (int j = 0; j < 4; ++j) acc[i][j] = 0.f;

    if (y2 >= 0 && y2 < NH) {
        const float* p1 = f1 + (b * NC * NH + y)  * NW + x0;
        const float* p2 = f2 + (b * NC * NH + y2) * NW + x0;
        const bool hasL = (x0 >= 4);        // left float4 fully in-bounds
        const bool hasR = (x0 <= NW - 8);   // right float4 fully in-bounds
#pragma unroll 2
        for (int c = 0; c < NC; ++c) {
            const float4 av = *(const float4*)p1;
            const float4 Lv = hasL ? *(const float4*)(p2 - 4) : make_float4(0.f, 0.f, 0.f, 0.f);
            const float4 Mv = *(const float4*)(p2);
            const float4 Rv = hasR ? *(const float4*)(p2 + 4) : make_float4(0.f, 0.f, 0.f, 0.f);
            const float w[12] = {Lv.x, Lv.y, Lv.z, Lv.w,
                                 Mv.x, Mv.y, Mv.z, Mv.w,
                                 Rv.x, Rv.y, Rv.z, Rv.w};
            const float a[4] = {av.x, av.y, av.z, av.w};
#pragma unroll
            for (int dxi = 0; dxi < NP; ++dxi)
#pragma unroll
                for (int j = 0; j < 4; ++j)
                    acc[dxi][j] += a[j] * w[dxi + j];  // f2[x0+j+dxi-4]
            p1 += PLANE;
            p2 += PLANE;
        }
    }

    // out[b][dyi*9+dxi][y][x0..x0+3]; dxi->dxi+1 stride = PLANE floats
    float* ob = out + ((b * (NP * NP) + dyi * NP) * NH + y) * NW + x0;
#pragma unroll
    for (int dxi = 0; dxi < NP; ++dxi) {
        *(float4*)ob = make_float4(acc[dxi][0], acc[dxi][1], acc[dxi][2], acc[dxi][3]);
        ob += PLANE;
    }
}

extern "C" void kernel_launch(void* const* d_in, const int* in_sizes, int n_in,
                              void* d_out, int out_size, void* d_ws, size_t ws_size,
                              hipStream_t stream) {
    const float* f1 = (const float*)d_in[0];
    const float* f2 = (const float*)d_in[1];
    float* out = (float*)d_out;
    dim3 grid(NP, NCHUNK / 64, 1);  // dy fastest -> dy-variants of a tile adjacent
    costvol_kernel<<<grid, dim3(64, 1, 1), 0, stream>>>(f1, f2, out);
}

// Round 2
// 48.194 us; speedup vs baseline: 1.7853x; 1.7853x over previous
//
#include <hip/hip_runtime.h>

// Cost volume: corr[b, dyi*9+dxi, y, x] = sum_c f1[b,c,y,x] * f2[b,c,y+dyi-4,x+dxi-4]
// (OOB f2 = 0). B=4, C=256, H=W=96, patch 9x9.
//
// Round 2:
//  - 256-thread blocks, 4-way channel split: wave w does channels [64w,64w+64)
//    for the same 64 x-chunks; two-stage LDS reduction combines the 4 partials.
//    5184 waves total (~5/SIMD) vs 1296 before (occupancy 13% -> ~60%).
//  - Whole grid (1296 blocks) co-resident (18.9 KB LDS, ~7 blocks/CU cap).
//  - Bijective XCD swizzle (1296 = 8*162): contiguous swz per XCD, dy fastest,
//    so a tile's 9 dy-variants share one XCD's L2 (kills the 3.4x over-fetch).

#define NB 4
#define NC 256
#define NH 96
#define NW 96
#define MAXD 4
#define NP 9
#define XCH (NW / 4)            // 24 x-chunks per row
#define NCHUNK (NB * NH * XCH)  // 9216 chunks
#define PLANE (NH * NW)         // 9216 floats per (b,c) plane
#define NGRP (NCHUNK / 64)      // 144 chunk-groups
#define NBLK (NP * NGRP)        // 1296 blocks
#define CPW (NC / 4)            // 64 channels per wave
#define LPAD 37                 // 36 acc floats padded to 37 (coprime with 32 banks)

__global__ __launch_bounds__(256) void costvol_kernel(
    const float* __restrict__ f1, const float* __restrict__ f2,
    float* __restrict__ out)
{
    __shared__ float lds[2 * 64 * LPAD];  // 18,944 B

    // XCD swizzle: consecutive blockIdx round-robin XCDs; remap so each XCD
    // owns a contiguous swz range. dy fastest within that range.
    const int bid = blockIdx.x;
    const int swz = (bid & 7) * (NBLK / 8) + (bid >> 3);
    const int dyi = swz % NP;
    const int g   = swz / NP;

    const int w    = threadIdx.x >> 6;   // wave 0..3
    const int lane = threadIdx.x & 63;

    const int chk = g * 64 + lane;       // 0..9215
    const int b   = chk / (NH * XCH);
    const int rem = chk - b * (NH * XCH);
    const int y   = rem / XCH;
    const int x0  = (rem - y * XCH) * 4;
    const int y2  = y + dyi - MAXD;

    float acc[NP][4];
#pragma unroll
    for (int i = 0; i < NP; ++i)
#pragma unroll
        for (int j = 0; j < 4; ++j) acc[i][j] = 0.f;

    if (y2 >= 0 && y2 < NH) {
        const float* p1 = f1 + ((b * NC + w * CPW) * NH + y)  * NW + x0;
        const float* p2 = f2 + ((b * NC + w * CPW) * NH + y2) * NW + x0;
        const bool hasL = (x0 >= 4);
        const bool hasR = (x0 <= NW - 8);
#pragma unroll 4
        for (int c = 0; c < CPW; ++c) {
            const float4 av = *(const float4*)p1;
            const float4 Lv = hasL ? *(const float4*)(p2 - 4) : make_float4(0.f, 0.f, 0.f, 0.f);
            const float4 Mv = *(const float4*)(p2);
            const float4 Rv = hasR ? *(const float4*)(p2 + 4) : make_float4(0.f, 0.f, 0.f, 0.f);
            const float wv[12] = {Lv.x, Lv.y, Lv.z, Lv.w,
                                  Mv.x, Mv.y, Mv.z, Mv.w,
                                  Rv.x, Rv.y, Rv.z, Rv.w};
            const float a[4] = {av.x, av.y, av.z, av.w};
#pragma unroll
            for (int dxi = 0; dxi < NP; ++dxi)
#pragma unroll
                for (int j = 0; j < 4; ++j)
                    acc[dxi][j] += a[j] * wv[dxi + j];
            p1 += PLANE;
            p2 += PLANE;
        }
    }

    // ---- two-stage cross-wave reduction (all barriers reached by all threads)
    float* reg0 = &lds[0 * 64 * LPAD + lane * LPAD];
    float* reg1 = &lds[1 * 64 * LPAD + lane * LPAD];

    if (w >= 2) {                       // stage 1 producers
        float* dst = (w == 2) ? reg0 : reg1;
#pragma unroll
        for (int dxi = 0; dxi < NP; ++dxi)
#pragma unroll
            for (int j = 0; j < 4; ++j) dst[dxi * 4 + j] = acc[dxi][j];
    }
    __syncthreads();
    if (w < 2) {                        // stage 1 consumers
        const float* src = (w == 0) ? reg0 : reg1;
#pragma unroll
        for (int dxi = 0; dxi < NP; ++dxi)
#pragma unroll
            for (int j = 0; j < 4; ++j) acc[dxi][j] += src[dxi * 4 + j];
    }
    __syncthreads();
    if (w == 1) {                       // stage 2 producer
#pragma unroll
        for (int dxi = 0; dxi < NP; ++dxi)
#pragma unroll
            for (int j = 0; j < 4; ++j) reg0[dxi * 4 + j] = acc[dxi][j];
    }
    __syncthreads();
    if (w == 0) {                       // stage 2 consumer + writeout
#pragma unroll
        for (int dxi = 0; dxi < NP; ++dxi)
#pragma unroll
            for (int j = 0; j < 4; ++j) acc[dxi][j] += reg0[dxi * 4 + j];

        float* ob = out + ((b * (NP * NP) + dyi * NP) * NH + y) * NW + x0;
#pragma unroll
        for (int dxi = 0; dxi < NP; ++dxi) {
            *(float4*)ob = make_float4(acc[dxi][0], acc[dxi][1], acc[dxi][2], acc[dxi][3]);
            ob += PLANE;
        }
    }
}

extern "C" void kernel_launch(void* const* d_in, const int* in_sizes, int n_in,
                              void* d_out, int out_size, void* d_ws, size_t ws_size,
                              hipStream_t stream) {
    const float* f1 = (const float*)d_in[0];
    const float* f2 = (const float*)d_in[1];
    float* out = (float*)d_out;
    costvol_kernel<<<dim3(NBLK, 1, 1), dim3(256, 1, 1), 0, stream>>>(f1, f2, out);
}